// Round 14
// baseline (258.269 us; speedup 1.0000x reference)
//
#include <hip/hip_runtime.h>
#include <hip/hip_bf16.h>

constexpr int NS   = 32;
constexpr int C    = 16;
constexpr int H    = 128;
constexpr int W    = 128;
constexpr int DS   = 5;
constexpr int M    = C * DS * DS;   // 400
constexpr int NLAG = 81;

typedef short short8 __attribute__((ext_vector_type(8)));
typedef float f32x4 __attribute__((ext_vector_type(4)));

// LDS ring layout (bf16): ring[slot=row&15][ch][152] ushort:
//   [8 zero][128 data][16 zero]  -> row-slot = 16ch*152*2 = 4864 B
// CH_U=152 -> channel stride 304 B == 12 dwords (mod 32): b128 reads ~2-way.
constexpr int CH_U    = 152;
constexpr int SLOT_U  = 16 * CH_U;            // 2432 us = 4864 B per row-slot
constexpr int SLOT_B  = SLOT_U * 2;           // 4864
constexpr int RING_B  = 16 * SLOT_B;          // 77824 B

// repacked-weight blob (built by mid kernel, DMA'd into solve's LDS):
constexpr int WREP_F  = 6 * 144 * 20 + 6 * 16;   // 17376 floats = 69504 B
constexpr int WREP_CH = WREP_F * 4 / 16;          // 4344 16B chunks

constexpr int PVP = 29;   // pv pitch: 29 mod 32 -> 16 distinct banks, bcast free

constexpr size_t RSZ  = (size_t)NS * C * C * NLAG;   // 663552 floats per R array
constexpr int    RSZ4 = (int)(RSZ / 4);              // 165888 float4s
constexpr int    CMB_BLOCKS = RSZ4 / 256;            // 648

__device__ __forceinline__ unsigned int pk_bf16(float a, float b) {
    union { __hip_bfloat162 h; unsigned int u; } cv;
    cv.h = __float22bfloat162_rn(make_float2(a, b));
    return cv.u;
}

__device__ __forceinline__ void gl_lds16(const void* g, void* l) {
    __builtin_amdgcn_global_load_lds(
        (const __attribute__((address_space(1))) unsigned int*)g,
        (__attribute__((address_space(3))) unsigned int*)l, 16, 0, 0);
}

// ---------------------------------------------------------------------------
// MFMA autocorr, split-H x 2 lag-groups: 256 blocks (1/CU, 8 waves).
// T14 async-STAGE split: per step, global x loads issue BEFORE the MFMA
// compute (into 16 VGPRs) and the vmcnt-wait + cvt + ds_write land AFTER it —
// the ~600-900cy HBM/L3 latency hides under ~3000cy of MFMA work instead of
// stalling every wave at the top of the step (R13: >=50% no-issue cycles).
// Write slots (s+8..s+11)&15 are disjoint from read window (s-4..s+7)&15.
// ---------------------------------------------------------------------------
__device__ __forceinline__ void stage_load(const float* __restrict__ xn,
                                           float4 (&v)[4], int row0, int tid)
{
    const int pair = tid >> 3;        // 0..63: rr*16+ch
    const int sub  = tid & 7;         // 16-float segment within row
    const int rr   = pair >> 4;
    const int ch   = pair & 15;
    const int row  = row0 + rr;
    const float4* src = (const float4*)(xn + ((size_t)ch * H + row) * W + sub * 16);
    v[0] = src[0]; v[1] = src[1]; v[2] = src[2]; v[3] = src[3];
}

__device__ __forceinline__ void stage_write(char* sm, const float4 (&v)[4],
                                            int row0, int tid)
{
    const int pair = tid >> 3;
    const int sub  = tid & 7;
    const int rr   = pair >> 4;
    const int ch   = pair & 15;
    const int row  = row0 + rr;       // rbase%16==0 so row&15==local&15
    unsigned short* dst = (unsigned short*)sm + (row & 15) * SLOT_U + ch * CH_U + 8 + sub * 16;
    *(uint4*)(dst)     = make_uint4(pk_bf16(v[0].x, v[0].y), pk_bf16(v[0].z, v[0].w),
                                    pk_bf16(v[1].x, v[1].y), pk_bf16(v[1].z, v[1].w));
    *(uint4*)(dst + 8) = make_uint4(pk_bf16(v[2].x, v[2].y), pk_bf16(v[2].z, v[2].w),
                                    pk_bf16(v[3].x, v[3].y), pk_bf16(v[3].z, v[3].w));
}

__device__ __forceinline__ void stage4(const float* __restrict__ xn,
                                       char* sm, int row0, int tid)
{
    float4 v[4];
    stage_load(xn, v, row0, tid);
    stage_write(sm, v, row0, tid);
}

template<int P0, int P1>
__device__ __forceinline__ void autocorr_body(const float* __restrict__ xn,
                                              float* __restrict__ Rn,
                                              char* sm, int tid, int rbase)
{
    constexpr int U0 = P0 / 9;
    constexpr int U1 = (P1 - 1) / 9;
    constexpr int NB = U1 - U0 + 1;
    constexpr int NP = P1 - P0;
    constexpr int SLOT_Q = SLOT_B / 16;      // 304 uint4 per row-slot

    unsigned short* ring = (unsigned short*)sm;
    const int lane = tid & 63;
    const int wid  = tid >> 6;
    const int q    = lane >> 4;
    const int mi   = lane & 15;
    const int rh   = wid & 3;
    const int chh  = wid >> 2;

    f32x4 acc[NP];
#pragma unroll
    for (int l = 0; l < NP; ++l) acc[l] = (f32x4){0.f, 0.f, 0.f, 0.f};

    if (rbase == 0) {
        for (int f = tid; f < 4 * SLOT_Q; f += 512)
            ((uint4*)sm)[(12 + f / SLOT_Q) * SLOT_Q + (f % SLOT_Q)] = make_uint4(0, 0, 0, 0);
        if (tid < 192) {
            const int slot = tid >> 4, ch = tid & 15;
            unsigned short* sb = ring + slot * SLOT_U + ch * CH_U;
            *(uint4*)(sb)       = make_uint4(0u, 0u, 0u, 0u);
            *(uint4*)(sb + 136) = make_uint4(0u, 0u, 0u, 0u);
            *(uint4*)(sb + 144) = make_uint4(0u, 0u, 0u, 0u);
        }
        stage4(xn, sm, 0, tid);
        stage4(xn, sm, 4, tid);
    } else {
        if (tid < 256) {
            const int slot = tid >> 4, ch = tid & 15;
            unsigned short* sb = ring + slot * SLOT_U + ch * CH_U;
            *(uint4*)(sb)       = make_uint4(0u, 0u, 0u, 0u);
            *(uint4*)(sb + 136) = make_uint4(0u, 0u, 0u, 0u);
            *(uint4*)(sb + 144) = make_uint4(0u, 0u, 0u, 0u);
        }
        stage4(xn, sm, 60, tid);   // rows 60..63 -> slots 12..15 (local -4..-1)
        stage4(xn, sm, 64, tid);
        stage4(xn, sm, 68, tid);
    }
    __syncthreads();

    for (int s = 0; s < 64; s += 4) {
        const bool pf = (s <= 52 || (s == 56 && rbase == 0));
        float4 sv[4];
        if (pf) stage_load(xn, sv, rbase + s + 8, tid);   // issue early

        const int r = s + rh;   // local row
        const unsigned short* rowA = ring + (r & 15) * SLOT_U + mi * CH_U;
#pragma unroll
        for (int cc = 0; cc < 2; ++cc) {
            const int w0 = (chh * 2 + cc) * 32;
            const uint4* pa = (const uint4*)(rowA + w0 + 8 * q);
            uint4 A0 = pa[0], A1 = pa[1], A2 = pa[2];
            unsigned int d[12] = {A0.x, A0.y, A0.z, A0.w, A1.x, A1.y, A1.z, A1.w,
                                  A2.x, A2.y, A2.z, A2.w};
            short8 bf[NB];
#pragma unroll
            for (int u = U0; u <= U1; ++u)
                bf[u - U0] = *(const short8*)(ring + ((r + u - 4 + 16) & 15) * SLOT_U +
                                              mi * CH_U + 8 + w0 + 8 * q);
#pragma unroll
            for (int v = 0; v < 9; ++v) {
                const int off = 12 - v;
                const int q4  = off >> 1;
                union { unsigned int u4[4]; short8 s8; } af;
                if (off & 1) {
#pragma unroll
                    for (int k2 = 0; k2 < 4; ++k2)
                        af.u4[k2] = (d[q4 + k2] >> 16) | (d[q4 + k2 + 1] << 16);
                } else {
#pragma unroll
                    for (int k2 = 0; k2 < 4; ++k2) af.u4[k2] = d[q4 + k2];
                }
#pragma unroll
                for (int u = U0; u <= U1; ++u) {
                    if (u * 9 + v >= P0 && u * 9 + v < P1)
                        acc[u * 9 + v - P0] = __builtin_amdgcn_mfma_f32_16x16x32_bf16(
                            af.s8, bf[u - U0], acc[u * 9 + v - P0], 0, 0, 0);
                }
            }
        }

        // write-late: vmcnt wait + convert + ds_write after the MFMA work
        if (pf) {
            stage_write(sm, sv, rbase + s + 8, tid);
        } else if (s == 56) {
            for (int f = tid; f < 4 * SLOT_Q; f += 512)
                ((uint4*)sm)[(((s + 8 + f / SLOT_Q) & 15)) * SLOT_Q + (f % SLOT_Q)] = make_uint4(0, 0, 0, 0);
        }
        __syncthreads();
    }

    float* sred = (float*)sm;
#pragma unroll
    for (int cb = 0; cb < NP; cb += 9) {
        const int nc = (NP - cb < 9) ? (NP - cb) : 9;
        __syncthreads();
#pragma unroll
        for (int pp = 0; pp < 9; ++pp) {
            if (pp < nc) {
#pragma unroll
                for (int rg = 0; rg < 4; ++rg)
                    sred[(pp * 8 + wid) * 256 + (q * 4 + rg) * 16 + mi] = acc[cb + pp][rg];
            }
        }
        __syncthreads();
        if (tid < 256) {
#pragma unroll
            for (int pp = 0; pp < 9; ++pp) {
                if (pp < nc) {
                    float ssum = 0.f;
#pragma unroll
                    for (int w8 = 0; w8 < 8; ++w8)
                        ssum += sred[(pp * 8 + w8) * 256 + tid];
                    Rn[(size_t)tid * NLAG + P0 + cb + pp] = ssum;   // plain store
                }
            }
        }
    }
}

__global__ __launch_bounds__(512, 1)
void autocorr_mfma(const float* __restrict__ x1, const float* __restrict__ x2,
                   float* __restrict__ R1a, float* __restrict__ R1b,
                   float* __restrict__ R2a, float* __restrict__ R2b)
{
    __shared__ __align__(16) char sm[RING_B];
    // 256 blocks = 8 XCDs x 8 slice-groups x (2 half x 2 lg).
    const int b = blockIdx.x;
    const int xcd = b & 7, k = b >> 3;          // k in [0,32)
    const int sl_local = k >> 2;                 // 8 slice-groups per XCD
    const int r2 = k & 3;
    const int half = r2 >> 1, lg = r2 & 1;
    const int slice = xcd * 8 + sl_local;        // [0,64)
    const int n = slice & 31, zi = slice >> 5;
    const int rbase = half * 64;
    const float* xn = (zi ? x2 : x1) + (size_t)n * C * H * W;
    float* Rbase = zi ? (half ? R2b : R2a) : (half ? R1b : R1a);
    float* Rn = Rbase + (size_t)n * C * C * NLAG;
    if (lg == 0) autocorr_body< 0, 41>(xn, Rn, sm, threadIdx.x, rbase);
    else         autocorr_body<41, 81>(xn, Rn, sm, threadIdx.x, rbase);
}

// ---------------------------------------------------------------------------
// mid kernel (replaces prep + combine dispatches):
//   blocks 0..1023   : crosscorr P (y-centric rolling window)  [x is L3-hot]
//   block 1024       : weight/bias repack into solve's LDS layout
//   blocks 1025..1672: combine R1a += R1b, R2a += R2b (float4)
// ---------------------------------------------------------------------------
__global__ __launch_bounds__(256, 1)
void mid_kernel(const float* __restrict__ x1, const float* __restrict__ x2,
                const float* __restrict__ y1, const float* __restrict__ y2,
                float* __restrict__ P1, float* __restrict__ P2,
                const float* __restrict__ w1, const float* __restrict__ b1,
                const float* __restrict__ w2, const float* __restrict__ b2,
                const float* __restrict__ w3, const float* __restrict__ b3,
                const float* __restrict__ w4, const float* __restrict__ b4,
                const float* __restrict__ w5, const float* __restrict__ b5,
                const float* __restrict__ w6, const float* __restrict__ b6,
                float* __restrict__ wrep,
                float* __restrict__ R1a, const float* __restrict__ R1b,
                float* __restrict__ R2a, const float* __restrict__ R2b)
{
    __shared__ float red[4][25];
    const int b = blockIdx.x, tid = threadIdx.x;
    if (b < 1024) {
        const int n = b & 31, j = (b >> 5) & 15, zi = b >> 9;
        const float* x = zi ? x2 : x1;
        const float* y = zi ? y2 : y1;
        float* P       = zi ? P2 : P1;

        const float* yn = y + (size_t)n * H * W;
        const float* xc = x + ((size_t)n * C + j) * H * W;

        const int wg = tid & 31, slab = tid >> 5;
        const int r0 = slab * 16;

        float acc[25];
#pragma unroll
        for (int l = 0; l < 25; ++l) acc[l] = 0.f;

        float4 yw[5];
#pragma unroll
        for (int u = 0; u < 5; ++u) {
            const int t = r0 + 1 - u;
            yw[u] = (t >= 0) ? *(const float4*)(yn + (size_t)t * W + wg * 4)
                             : make_float4(0.f, 0.f, 0.f, 0.f);
        }

#pragma unroll 4
        for (int rr = 0; rr < 16; ++rr) {
            const int r = r0 + rr;
#pragma unroll
            for (int u = 4; u >= 1; --u) yw[u] = yw[u - 1];
            const int tnew = r + 2;
            yw[0] = (tnew < H) ? *(const float4*)(yn + (size_t)tnew * W + wg * 4)
                               : make_float4(0.f, 0.f, 0.f, 0.f);

            const float* xr = xc + (size_t)r * W + wg * 4;
            float w12[12];
            float4 t4 = (wg > 0) ? *(const float4*)(xr - 4) : make_float4(0, 0, 0, 0);
            w12[0] = t4.x; w12[1] = t4.y; w12[2] = t4.z; w12[3] = t4.w;
            t4 = *(const float4*)(xr);
            w12[4] = t4.x; w12[5] = t4.y; w12[6] = t4.z; w12[7] = t4.w;
            t4 = (wg < 31) ? *(const float4*)(xr + 4) : make_float4(0, 0, 0, 0);
            w12[8] = t4.x; w12[9] = t4.y; w12[10] = t4.z; w12[11] = t4.w;

#pragma unroll
            for (int u = 0; u < 5; ++u) {
#pragma unroll
                for (int v = 0; v < 5; ++v)
                    acc[u * 5 + v] += yw[u].x * w12[2 + v] + yw[u].y * w12[3 + v] +
                                      yw[u].z * w12[4 + v] + yw[u].w * w12[5 + v];
            }
        }

        const int lane = tid & 63, wv = tid >> 6;
#pragma unroll
        for (int l = 0; l < 25; ++l) {
            float v = acc[l];
#pragma unroll
            for (int off = 32; off; off >>= 1) v += __shfl_down(v, off);
            if (lane == 0) red[wv][l] = v;
        }
        __syncthreads();
        if (tid < 25)
            P[((size_t)n * C + j) * 25 + tid] = red[0][tid] + red[1][tid] + red[2][tid] + red[3][tid];
        return;
    }
    if (b == 1024) {
        // weight/bias repack into solve's LDS layout.
        const float* wsl[6] = {w1, w2, w3, w4, w5, w6};
        const float* bsl[6] = {b1, b2, b3, b4, b5, b6};
#pragma unroll
        for (int l = 0; l < 6; ++l) {
            const int cin = (l == 0) ? 17 : 16;
            const float* ws = wsl[l];
            for (int f = tid; f < 16 * cin * 9; f += 256) {
                const int o = f / (cin * 9);
                const int rm = f - o * cin * 9;
                const int ci = rm / 9, kk = rm - ci * 9;
                wrep[l * 2880 + (o * 9 + kk) * 20 + ci] = ws[f];
            }
            if (tid < 16) wrep[17280 + l * 16 + tid] = bsl[l][tid];
        }
        return;
    }
    // combine blocks
    const int i = (b - 1025) * 256 + tid;
    if (i < RSZ4) {
        float4 a = ((float4*)R1a)[i], bb = ((const float4*)R1b)[i];
        a.x += bb.x; a.y += bb.y; a.z += bb.z; a.w += bb.w;
        ((float4*)R1a)[i] = a;
        float4 c = ((float4*)R2a)[i], d = ((const float4*)R2b)[i];
        c.x += d.x; c.y += d.y; c.z += d.z; c.w += d.w;
        ((float4*)R2a)[i] = c;
    }
}

// ---------------------------------------------------------------------------
// fused solve: CG1 (3 it) + CG2 (7 it) + 6-layer CNN; 256 threads/block.
// Chronopoulos-fused reduction: one float2 block-reduce per iteration.
// ---------------------------------------------------------------------------
__device__ __forceinline__ float block_sum256(float v, float* red, int t)
{
#pragma unroll
    for (int off = 32; off; off >>= 1) v += __shfl_down(v, off);
    if ((t & 63) == 0) red[t >> 6] = v;
    __syncthreads();
    float s = red[0] + red[1] + red[2] + red[3];
    __syncthreads();
    return s;
}

__device__ __forceinline__ float2 block_sum256_f2(float v0, float v1, float* red, int t)
{
#pragma unroll
    for (int off = 32; off; off >>= 1) { v0 += __shfl_down(v0, off); v1 += __shfl_down(v1, off); }
    if ((t & 63) == 0) { red[(t >> 6) * 2] = v0; red[(t >> 6) * 2 + 1] = v1; }
    __syncthreads();
    const float s0 = red[0] + red[2] + red[4] + red[6];
    const float s1 = red[1] + red[3] + red[5] + red[7];
    __syncthreads();
    return make_float2(s0, s1);
}

__device__ __forceinline__ void cg_solve(const float (&Rreg)[81],
                                         float rhs0, float rhs1,
                                         int iters, float a, int t, bool has1,
                                         float* pv, float* ap, float* red,
                                         float& z0o, float& z1o)
{
    const int jj = t & 15;
    const int e1 = t + 256;
    float z0 = 0.f, z1 = 0.f;
    float r0 = rhs0, r1 = has1 ? rhs1 : 0.f;
    float p0 = r0, p1 = r1;
    pv[(t / 25) * PVP + (t % 25)] = p0;
    if (has1) pv[(e1 / 25) * PVP + (e1 % 25)] = p1;
    float rr = block_sum256(r0 * r0 + r1 * r1, red, t);   // syncs cover pv writes

    for (int it = 0; it < iters; ++it) {
        float pld[25], acc[25];
        const float* pj = &pv[jj * PVP];
#pragma unroll
        for (int k = 0; k < 25; ++k) pld[k] = pj[k];
#pragma unroll
        for (int k = 0; k < 25; ++k) acc[k] = 0.f;
#pragma unroll
        for (int u = 0; u < 9; ++u) {
#pragma unroll
            for (int v = 0; v < 9; ++v) {
                const float Rv = Rreg[u * 9 + v];          // register (static idx)
#pragma unroll
                for (int c = 0; c < 5; ++c) {
                    if (c < u - 4 || c > u) continue;
                    const int aa = 4 + c - u;
#pragma unroll
                    for (int dd = 0; dd < 5; ++dd) {
                        if (dd < v - 4 || dd > v) continue;
                        const int bb = 4 + dd - v;
                        acc[aa * 5 + bb] += Rv * pld[c * 5 + dd];
                    }
                }
            }
        }
#pragma unroll
        for (int k = 0; k < 25; ++k) {
            float s2 = acc[k];
            s2 += __shfl_down(s2, 8, 16);
            s2 += __shfl_down(s2, 4, 16);
            s2 += __shfl_down(s2, 2, 16);
            s2 += __shfl_down(s2, 1, 16);
            acc[k] = s2;
        }
        if (jj == 0) {
#pragma unroll
            for (int k = 0; k < 25; ++k) ap[(t >> 4) * 25 + k] = acc[k];
        }
        __syncthreads();
        const float w0 = ap[t] + a * p0;
        const float w1 = has1 ? (ap[e1] + a * p1) : 0.f;
        const float2 dots = block_sum256_f2(p0 * w0 + p1 * w1,
                                            w0 * w0 + w1 * w1, red, t);
        const float pAp = dots.x, ww = dots.y;
        const bool ok = (pAp > 1e-30f);
        const float al  = ok ? rr / pAp : 0.f;
        z0 += al * p0; z1 += al * p1;
        if (it + 1 < iters) {
            const float rrn = ok ? fmaxf(al * al * ww - rr, 0.f) : rr;  // (r,w)=pAp
            const float be  = (rr > 1e-30f) ? rrn / rr : 0.f;
            rr = rrn;
            r0 -= al * w0; r1 -= al * w1;
            p0 = r0 + be * p0; p1 = r1 + be * p1;
            pv[(t / 25) * PVP + (t % 25)] = p0;
            if (has1) pv[(e1 / 25) * PVP + (e1 % 25)] = p1;
            __syncthreads();
        }
    }
    z0o = z0; z1o = z1;
}

__device__ __forceinline__ float conv_one(const float* __restrict__ act,
                                          const float* __restrict__ wall,
                                          int l, int idx)
{
    const int o = idx / 25, pix = idx % 25, yy = pix / 5, xx = pix % 5;
    float s = wall[17280 + l * 16 + o];
#pragma unroll
    for (int ky = 0; ky < 3; ++ky) {
        const int iy = yy + ky - 1;
        if ((unsigned)iy >= 5u) continue;
#pragma unroll
        for (int kx = 0; kx < 3; ++kx) {
            const int ix = xx + kx - 1;
            if ((unsigned)ix >= 5u) continue;
            const float* ip = act + (iy * 5 + ix) * 20;
            const float* wp = wall + l * 2880 + (o * 9 + ky * 3 + kx) * 20;
            const float4 a0 = *(const float4*)(ip);
            const float4 a1 = *(const float4*)(ip + 4);
            const float4 a2 = *(const float4*)(ip + 8);
            const float4 a3 = *(const float4*)(ip + 12);
            const float4 q0 = *(const float4*)(wp);
            const float4 q1 = *(const float4*)(wp + 4);
            const float4 q2 = *(const float4*)(wp + 8);
            const float4 q3 = *(const float4*)(wp + 12);
            s += a0.x * q0.x + a0.y * q0.y + a0.z * q0.z + a0.w * q0.w
               + a1.x * q1.x + a1.y * q1.y + a1.z * q1.z + a1.w * q1.w
               + a2.x * q2.x + a2.y * q2.y + a2.z * q2.z + a2.w * q2.w
               + a3.x * q3.x + a3.y * q3.y + a3.z * q3.z + a3.w * q3.w;
            if (l == 0) s += ip[16] * wp[16];
        }
    }
    return s;
}

__global__ __launch_bounds__(256, 1)
void solve_kernel(const float* __restrict__ R1, const float* __restrict__ R2,
                  const float* __restrict__ P1, const float* __restrict__ P2,
                  const float* __restrict__ d0, const float* __restrict__ alpha,
                  const float* __restrict__ beta, const float* __restrict__ reg,
                  const float* __restrict__ wrep,
                  float* __restrict__ out)
{
    __shared__ __align__(16) float Rl[256 * NLAG];   // 82944 B; weight overlay later
    __shared__ float pv[16 * PVP];
    __shared__ float ap[M];
    __shared__ float red[8];
    __shared__ float h0p[25 * 20];
    __shared__ float bufA[25 * 20], bufB[25 * 20];

    const int n = blockIdx.x, t = threadIdx.x;
    const bool has1 = (t < M - 256);   // t < 144
    const int e1 = t + 256;
    const float a = alpha[n] * (float)(H * W) * reg[0] / (float)(DS * DS * C);

    // stage R1 -> LDS (flat linear, async dma)
    {
        const char* g = (const char*)(R1 + (size_t)n * 256 * NLAG);
        char* l = (char*)Rl;
        for (int f = t; f < 5184; f += 256)
            gl_lds16(g + (size_t)f * 16, l + (size_t)f * 16);
    }
    const float rhs10 = P1[(size_t)n * M + t] + a * d0[(size_t)n * M + t];
    const float rhs11 = has1 ? (P1[(size_t)n * M + e1] + a * d0[(size_t)n * M + e1]) : 0.f;
    __syncthreads();   // drains the DMA

    float Rreg[81];
    {
        const float* Rrow = &Rl[t * NLAG];
#pragma unroll
        for (int i = 0; i < 81; ++i) Rreg[i] = Rrow[i];
    }
    __syncthreads();   // all Rl reads done before overwrite

    // issue R2 -> Rl DMA; completes under CG1 (drained at its first barrier)
    {
        const char* g = (const char*)(R2 + (size_t)n * 256 * NLAG);
        char* l = (char*)Rl;
        for (int f = t; f < 5184; f += 256)
            gl_lds16(g + (size_t)f * 16, l + (size_t)f * 16);
    }
    float z1a, z1b;
    cg_solve(Rreg, rhs10, rhs11, 3, a, t, has1, pv, ap, red, z1a, z1b);
    // CG1 passed many barriers -> Rl holds R2 now
    __syncthreads();   // ensure all waves past CG1 tail before Rreg reload
    {
        const float* Rrow = &Rl[t * NLAG];
#pragma unroll
        for (int i = 0; i < 81; ++i) Rreg[i] = Rrow[i];
    }
    __syncthreads();   // Rl reads done

    // issue weight-blob DMA into Rl overlay; completes under CG2
    {
        const char* g = (const char*)wrep;
        char* l = (char*)Rl;
        for (int f = t; f < WREP_CH; f += 256)
            gl_lds16(g + (size_t)f * 16, l + (size_t)f * 16);
    }
    const float rhs20 = P2[(size_t)n * M + t] + a * z1a;
    const float rhs21 = has1 ? (P2[(size_t)n * M + e1] + a * z1b) : 0.f;
    float z20, z21;
    cg_solve(Rreg, rhs20, rhs21, 7, a, t, has1, pv, ap, red, z20, z21);

    // ---- CNN. Activations [pix][ch] pitch 20; weights pre-repacked in Rl.
    const float* wall = (const float*)Rl;
    h0p[(t % 25) * 20 + t / 25] = z20;
    if (has1) h0p[(e1 % 25) * 20 + e1 / 25] = z21;
    if (t < 25) h0p[t * 20 + 16] = rsqrtf(beta[n]);
    __syncthreads();

#pragma unroll
    for (int l = 0; l < 6; ++l) {
        const float* act = (l == 0) ? h0p : ((l & 1) ? bufA : bufB);
        float s0 = conv_one(act, wall, l, t);
        float s1 = has1 ? conv_one(act, wall, l, e1) : 0.f;
        if (l < 5) { s0 = fmaxf(s0, 0.f); s1 = fmaxf(s1, 0.f); }
        else {
            s0 += h0p[(t % 25) * 20 + t / 25];
            if (has1) s1 += h0p[(e1 % 25) * 20 + e1 / 25];
        }
        if (l == 5) {
            out[(size_t)n * M + t] = s0;
            if (has1) out[(size_t)n * M + e1] = s1;
        } else {
            float* dstb = (l & 1) ? bufB : bufA;   // never aliases act
            dstb[(t % 25) * 20 + t / 25] = s0;
            if (has1) dstb[(e1 % 25) * 20 + e1 / 25] = s1;
        }
        __syncthreads();
    }
}

// ---------------------------------------------------------------------------
extern "C" void kernel_launch(void* const* d_in, const int* in_sizes, int n_in,
                              void* d_out, int out_size, void* d_ws, size_t ws_size,
                              hipStream_t stream)
{
    (void)in_sizes; (void)n_in; (void)out_size; (void)ws_size;
    const float* x1    = (const float*)d_in[0];
    const float* x2    = (const float*)d_in[1];
    const float* d0    = (const float*)d_in[2];
    const float* y1    = (const float*)d_in[3];
    const float* y2    = (const float*)d_in[4];
    const float* alpha = (const float*)d_in[5];
    const float* beta  = (const float*)d_in[6];
    const float* reg   = (const float*)d_in[7];
    const float* w1 = (const float*)d_in[8];  const float* b1 = (const float*)d_in[9];
    const float* w2 = (const float*)d_in[10]; const float* b2 = (const float*)d_in[11];
    const float* w3 = (const float*)d_in[12]; const float* b3 = (const float*)d_in[13];
    const float* w4 = (const float*)d_in[14]; const float* b4 = (const float*)d_in[15];
    const float* w5 = (const float*)d_in[16]; const float* b5 = (const float*)d_in[17];
    const float* w6 = (const float*)d_in[18]; const float* b6 = (const float*)d_in[19];
    float* out = (float*)d_out;

    char* wsb = (char*)d_ws;
    float* R1a = (float*)wsb;
    float* R1b = R1a + RSZ;
    float* R2a = R1b + RSZ;
    float* R2b = R2a + RSZ;
    float* P1  = R2b + RSZ;
    float* P2  = P1 + (size_t)NS * M;
    float* wrep = P2 + (size_t)NS * M;                         // 17376 floats

    autocorr_mfma<<<256, 512, 0, stream>>>(x1, x2, R1a, R1b, R2a, R2b);
    mid_kernel<<<1025 + CMB_BLOCKS, 256, 0, stream>>>(x1, x2, y1, y2, P1, P2,
                                                      w1, b1, w2, b2, w3, b3,
                                                      w4, b4, w5, b5, w6, b6,
                                                      wrep, R1a, R1b, R2a, R2b);
    solve_kernel<<<NS, 256, 0, stream>>>(R1a, R2a, P1, P2, d0, alpha, beta, reg,
                                         wrep, out);
}

// Round 15
// 247.142 us; speedup vs baseline: 1.0450x; 1.0450x over previous
//
#include <hip/hip_runtime.h>
#include <hip/hip_bf16.h>

constexpr int NS   = 32;
constexpr int C    = 16;
constexpr int H    = 128;
constexpr int W    = 128;
constexpr int DS   = 5;
constexpr int M    = C * DS * DS;   // 400
constexpr int NLAG = 81;

typedef short short8 __attribute__((ext_vector_type(8)));
typedef float f32x4 __attribute__((ext_vector_type(4)));

// LDS ring layout (bf16): ring[slot=row&15][ch][152] ushort:
//   [8 zero][128 data][16 zero]  -> row-slot = 16ch*152*2 = 4864 B
// CH_U=152 -> channel stride 304 B == 12 dwords (mod 32): b128 reads ~2-way.
constexpr int CH_U    = 152;
constexpr int SLOT_U  = 16 * CH_U;            // 2432 us = 4864 B per row-slot
constexpr int SLOT_B  = SLOT_U * 2;           // 4864
constexpr int RING_B  = 16 * SLOT_B;          // 77824 B

// repacked-weight blob (built by mid kernel, DMA'd into solve's LDS):
constexpr int WREP_F  = 6 * 144 * 20 + 6 * 16;   // 17376 floats = 69504 B
constexpr int WREP_CH = WREP_F * 4 / 16;          // 4344 16B chunks

constexpr int PVP = 29;   // pv pitch: 29 mod 32 -> 16 distinct banks, bcast free

constexpr size_t RSZ  = (size_t)NS * C * C * NLAG;   // 663552 floats per R array
constexpr int    RSZ4 = (int)(RSZ / 4);              // 165888 float4s
constexpr int    CMB_BLOCKS = RSZ4 / 256;            // 648

__device__ __forceinline__ unsigned int pk_bf16(float a, float b) {
    union { __hip_bfloat162 h; unsigned int u; } cv;
    cv.h = __float22bfloat162_rn(make_float2(a, b));
    return cv.u;
}

__device__ __forceinline__ void gl_lds16(const void* g, void* l) {
    __builtin_amdgcn_global_load_lds(
        (const __attribute__((address_space(1))) unsigned int*)g,
        (__attribute__((address_space(3))) unsigned int*)l, 16, 0, 0);
}

// ---------------------------------------------------------------------------
// MFMA autocorr, split-H x 2 lag-groups: 256 blocks (1/CU, 8 waves).
// stage4 at step top (R13 structure — T14 split spilled, reverted).
// Epilogue sred tile index is (rg*4+q)*16+mi (not (q*4+rg)): puts 16q into
// the bank index so scalar writes are 2-way instead of 4-way (64q==0 mod 32
// made q-lanes collide). Reader uses the inverse permutation.
// ---------------------------------------------------------------------------
__device__ __forceinline__ void stage4(const float* __restrict__ xn,
                                       char* sm, int row0, int tid)
{
    const int pair = tid >> 3;        // 0..63: rr*16+ch
    const int sub  = tid & 7;         // 16-float segment within row
    const int rr   = pair >> 4;
    const int ch   = pair & 15;
    const int row  = row0 + rr;       // global row; rbase%16==0 so row&15==local&15
    const float4* src = (const float4*)(xn + ((size_t)ch * H + row) * W + sub * 16);
    const float4 a = src[0], b = src[1], c = src[2], d = src[3];
    unsigned short* dst = (unsigned short*)sm + (row & 15) * SLOT_U + ch * CH_U + 8 + sub * 16;
    *(uint4*)(dst)     = make_uint4(pk_bf16(a.x, a.y), pk_bf16(a.z, a.w),
                                    pk_bf16(b.x, b.y), pk_bf16(b.z, b.w));
    *(uint4*)(dst + 8) = make_uint4(pk_bf16(c.x, c.y), pk_bf16(c.z, c.w),
                                    pk_bf16(d.x, d.y), pk_bf16(d.z, d.w));
}

template<int P0, int P1>
__device__ __forceinline__ void autocorr_body(const float* __restrict__ xn,
                                              float* __restrict__ Rn,
                                              char* sm, int tid, int rbase)
{
    constexpr int U0 = P0 / 9;
    constexpr int U1 = (P1 - 1) / 9;
    constexpr int NB = U1 - U0 + 1;
    constexpr int NP = P1 - P0;
    constexpr int SLOT_Q = SLOT_B / 16;      // 304 uint4 per row-slot

    unsigned short* ring = (unsigned short*)sm;
    const int lane = tid & 63;
    const int wid  = tid >> 6;
    const int q    = lane >> 4;
    const int mi   = lane & 15;
    const int rh   = wid & 3;
    const int chh  = wid >> 2;

    f32x4 acc[NP];
#pragma unroll
    for (int l = 0; l < NP; ++l) acc[l] = (f32x4){0.f, 0.f, 0.f, 0.f};

    if (rbase == 0) {
        for (int f = tid; f < 4 * SLOT_Q; f += 512)
            ((uint4*)sm)[(12 + f / SLOT_Q) * SLOT_Q + (f % SLOT_Q)] = make_uint4(0, 0, 0, 0);
        if (tid < 192) {
            const int slot = tid >> 4, ch = tid & 15;
            unsigned short* sb = ring + slot * SLOT_U + ch * CH_U;
            *(uint4*)(sb)       = make_uint4(0u, 0u, 0u, 0u);
            *(uint4*)(sb + 136) = make_uint4(0u, 0u, 0u, 0u);
            *(uint4*)(sb + 144) = make_uint4(0u, 0u, 0u, 0u);
        }
        stage4(xn, sm, 0, tid);
        stage4(xn, sm, 4, tid);
    } else {
        if (tid < 256) {
            const int slot = tid >> 4, ch = tid & 15;
            unsigned short* sb = ring + slot * SLOT_U + ch * CH_U;
            *(uint4*)(sb)       = make_uint4(0u, 0u, 0u, 0u);
            *(uint4*)(sb + 136) = make_uint4(0u, 0u, 0u, 0u);
            *(uint4*)(sb + 144) = make_uint4(0u, 0u, 0u, 0u);
        }
        stage4(xn, sm, 60, tid);   // rows 60..63 -> slots 12..15 (local -4..-1)
        stage4(xn, sm, 64, tid);
        stage4(xn, sm, 68, tid);
    }
    __syncthreads();

    for (int s = 0; s < 64; s += 4) {
        if (s <= 52 || (s == 56 && rbase == 0)) {
            stage4(xn, sm, rbase + s + 8, tid);
        } else if (s == 56) {
            for (int f = tid; f < 4 * SLOT_Q; f += 512)
                ((uint4*)sm)[(((s + 8 + f / SLOT_Q) & 15)) * SLOT_Q + (f % SLOT_Q)] = make_uint4(0, 0, 0, 0);
        }

        const int r = s + rh;   // local row
        const unsigned short* rowA = ring + (r & 15) * SLOT_U + mi * CH_U;
#pragma unroll
        for (int cc = 0; cc < 2; ++cc) {
            const int w0 = (chh * 2 + cc) * 32;
            const uint4* pa = (const uint4*)(rowA + w0 + 8 * q);
            uint4 A0 = pa[0], A1 = pa[1], A2 = pa[2];
            unsigned int d[12] = {A0.x, A0.y, A0.z, A0.w, A1.x, A1.y, A1.z, A1.w,
                                  A2.x, A2.y, A2.z, A2.w};
            short8 bf[NB];
#pragma unroll
            for (int u = U0; u <= U1; ++u)
                bf[u - U0] = *(const short8*)(ring + ((r + u - 4 + 16) & 15) * SLOT_U +
                                              mi * CH_U + 8 + w0 + 8 * q);
#pragma unroll
            for (int v = 0; v < 9; ++v) {
                const int off = 12 - v;
                const int q4  = off >> 1;
                union { unsigned int u4[4]; short8 s8; } af;
                if (off & 1) {
#pragma unroll
                    for (int k2 = 0; k2 < 4; ++k2)
                        af.u4[k2] = (d[q4 + k2] >> 16) | (d[q4 + k2 + 1] << 16);
                } else {
#pragma unroll
                    for (int k2 = 0; k2 < 4; ++k2) af.u4[k2] = d[q4 + k2];
                }
#pragma unroll
                for (int u = U0; u <= U1; ++u) {
                    if (u * 9 + v >= P0 && u * 9 + v < P1)
                        acc[u * 9 + v - P0] = __builtin_amdgcn_mfma_f32_16x16x32_bf16(
                            af.s8, bf[u - U0], acc[u * 9 + v - P0], 0, 0, 0);
                }
            }
        }
        __syncthreads();
    }

    // epilogue: permuted tile index (rg*4+q)*16+mi -> 2-way banks on writes
    float* sred = (float*)sm;
    const int qr   = tid >> 4;                       // for reader threads <256
    const int pidx = (((qr & 3) * 4) + (qr >> 2)) * 16 + (tid & 15);
#pragma unroll
    for (int cb = 0; cb < NP; cb += 9) {
        const int nc = (NP - cb < 9) ? (NP - cb) : 9;
        __syncthreads();
#pragma unroll
        for (int pp = 0; pp < 9; ++pp) {
            if (pp < nc) {
#pragma unroll
                for (int rg = 0; rg < 4; ++rg)
                    sred[(pp * 8 + wid) * 256 + (rg * 4 + q) * 16 + mi] = acc[cb + pp][rg];
            }
        }
        __syncthreads();
        if (tid < 256) {
#pragma unroll
            for (int pp = 0; pp < 9; ++pp) {
                if (pp < nc) {
                    float ssum = 0.f;
#pragma unroll
                    for (int w8 = 0; w8 < 8; ++w8)
                        ssum += sred[(pp * 8 + w8) * 256 + pidx];
                    Rn[(size_t)tid * NLAG + P0 + cb + pp] = ssum;   // plain store
                }
            }
        }
    }
}

__global__ __launch_bounds__(512, 1)
void autocorr_mfma(const float* __restrict__ x1, const float* __restrict__ x2,
                   float* __restrict__ R1a, float* __restrict__ R1b,
                   float* __restrict__ R2a, float* __restrict__ R2b)
{
    __shared__ __align__(16) char sm[RING_B];
    // 256 blocks = 8 XCDs x 8 slice-groups x (2 half x 2 lg).
    const int b = blockIdx.x;
    const int xcd = b & 7, k = b >> 3;          // k in [0,32)
    const int sl_local = k >> 2;                 // 8 slice-groups per XCD
    const int r2 = k & 3;
    const int half = r2 >> 1, lg = r2 & 1;
    const int slice = xcd * 8 + sl_local;        // [0,64)
    const int n = slice & 31, zi = slice >> 5;
    const int rbase = half * 64;
    const float* xn = (zi ? x2 : x1) + (size_t)n * C * H * W;
    float* Rbase = zi ? (half ? R2b : R2a) : (half ? R1b : R1a);
    float* Rn = Rbase + (size_t)n * C * C * NLAG;
    if (lg == 0) autocorr_body< 0, 41>(xn, Rn, sm, threadIdx.x, rbase);
    else         autocorr_body<41, 81>(xn, Rn, sm, threadIdx.x, rbase);
}

// ---------------------------------------------------------------------------
// mid kernel (replaces prep + combine dispatches):
//   blocks 0..1023   : crosscorr P (y-centric rolling window)  [x is L3-hot]
//   block 1024       : weight/bias repack into solve's LDS layout
//   blocks 1025..1672: combine R1a += R1b, R2a += R2b (float4)
// ---------------------------------------------------------------------------
__global__ __launch_bounds__(256, 1)
void mid_kernel(const float* __restrict__ x1, const float* __restrict__ x2,
                const float* __restrict__ y1, const float* __restrict__ y2,
                float* __restrict__ P1, float* __restrict__ P2,
                const float* __restrict__ w1, const float* __restrict__ b1,
                const float* __restrict__ w2, const float* __restrict__ b2,
                const float* __restrict__ w3, const float* __restrict__ b3,
                const float* __restrict__ w4, const float* __restrict__ b4,
                const float* __restrict__ w5, const float* __restrict__ b5,
                const float* __restrict__ w6, const float* __restrict__ b6,
                float* __restrict__ wrep,
                float* __restrict__ R1a, const float* __restrict__ R1b,
                float* __restrict__ R2a, const float* __restrict__ R2b)
{
    __shared__ float red[4][25];
    const int b = blockIdx.x, tid = threadIdx.x;
    if (b < 1024) {
        const int n = b & 31, j = (b >> 5) & 15, zi = b >> 9;
        const float* x = zi ? x2 : x1;
        const float* y = zi ? y2 : y1;
        float* P       = zi ? P2 : P1;

        const float* yn = y + (size_t)n * H * W;
        const float* xc = x + ((size_t)n * C + j) * H * W;

        const int wg = tid & 31, slab = tid >> 5;
        const int r0 = slab * 16;

        float acc[25];
#pragma unroll
        for (int l = 0; l < 25; ++l) acc[l] = 0.f;

        float4 yw[5];
#pragma unroll
        for (int u = 0; u < 5; ++u) {
            const int t = r0 + 1 - u;
            yw[u] = (t >= 0) ? *(const float4*)(yn + (size_t)t * W + wg * 4)
                             : make_float4(0.f, 0.f, 0.f, 0.f);
        }

#pragma unroll 4
        for (int rr = 0; rr < 16; ++rr) {
            const int r = r0 + rr;
#pragma unroll
            for (int u = 4; u >= 1; --u) yw[u] = yw[u - 1];
            const int tnew = r + 2;
            yw[0] = (tnew < H) ? *(const float4*)(yn + (size_t)tnew * W + wg * 4)
                               : make_float4(0.f, 0.f, 0.f, 0.f);

            const float* xr = xc + (size_t)r * W + wg * 4;
            float w12[12];
            float4 t4 = (wg > 0) ? *(const float4*)(xr - 4) : make_float4(0, 0, 0, 0);
            w12[0] = t4.x; w12[1] = t4.y; w12[2] = t4.z; w12[3] = t4.w;
            t4 = *(const float4*)(xr);
            w12[4] = t4.x; w12[5] = t4.y; w12[6] = t4.z; w12[7] = t4.w;
            t4 = (wg < 31) ? *(const float4*)(xr + 4) : make_float4(0, 0, 0, 0);
            w12[8] = t4.x; w12[9] = t4.y; w12[10] = t4.z; w12[11] = t4.w;

#pragma unroll
            for (int u = 0; u < 5; ++u) {
#pragma unroll
                for (int v = 0; v < 5; ++v)
                    acc[u * 5 + v] += yw[u].x * w12[2 + v] + yw[u].y * w12[3 + v] +
                                      yw[u].z * w12[4 + v] + yw[u].w * w12[5 + v];
            }
        }

        const int lane = tid & 63, wv = tid >> 6;
#pragma unroll
        for (int l = 0; l < 25; ++l) {
            float v = acc[l];
#pragma unroll
            for (int off = 32; off; off >>= 1) v += __shfl_down(v, off);
            if (lane == 0) red[wv][l] = v;
        }
        __syncthreads();
        if (tid < 25)
            P[((size_t)n * C + j) * 25 + tid] = red[0][tid] + red[1][tid] + red[2][tid] + red[3][tid];
        return;
    }
    if (b == 1024) {
        // weight/bias repack into solve's LDS layout.
        const float* wsl[6] = {w1, w2, w3, w4, w5, w6};
        const float* bsl[6] = {b1, b2, b3, b4, b5, b6};
#pragma unroll
        for (int l = 0; l < 6; ++l) {
            const int cin = (l == 0) ? 17 : 16;
            const float* ws = wsl[l];
            for (int f = tid; f < 16 * cin * 9; f += 256) {
                const int o = f / (cin * 9);
                const int rm = f - o * cin * 9;
                const int ci = rm / 9, kk = rm - ci * 9;
                wrep[l * 2880 + (o * 9 + kk) * 20 + ci] = ws[f];
            }
            if (tid < 16) wrep[17280 + l * 16 + tid] = bsl[l][tid];
        }
        return;
    }
    // combine blocks
    const int i = (b - 1025) * 256 + tid;
    if (i < RSZ4) {
        float4 a = ((float4*)R1a)[i], bb = ((const float4*)R1b)[i];
        a.x += bb.x; a.y += bb.y; a.z += bb.z; a.w += bb.w;
        ((float4*)R1a)[i] = a;
        float4 c = ((float4*)R2a)[i], d = ((const float4*)R2b)[i];
        c.x += d.x; c.y += d.y; c.z += d.z; c.w += d.w;
        ((float4*)R2a)[i] = c;
    }
}

// ---------------------------------------------------------------------------
// fused solve: CG1 (3 it) + CG2 (7 it) + 6-layer CNN; 256 threads/block.
// Chronopoulos-fused reduction: one float2 block-reduce per iteration.
// ---------------------------------------------------------------------------
__device__ __forceinline__ float block_sum256(float v, float* red, int t)
{
#pragma unroll
    for (int off = 32; off; off >>= 1) v += __shfl_down(v, off);
    if ((t & 63) == 0) red[t >> 6] = v;
    __syncthreads();
    float s = red[0] + red[1] + red[2] + red[3];
    __syncthreads();
    return s;
}

__device__ __forceinline__ float2 block_sum256_f2(float v0, float v1, float* red, int t)
{
#pragma unroll
    for (int off = 32; off; off >>= 1) { v0 += __shfl_down(v0, off); v1 += __shfl_down(v1, off); }
    if ((t & 63) == 0) { red[(t >> 6) * 2] = v0; red[(t >> 6) * 2 + 1] = v1; }
    __syncthreads();
    const float s0 = red[0] + red[2] + red[4] + red[6];
    const float s1 = red[1] + red[3] + red[5] + red[7];
    __syncthreads();
    return make_float2(s0, s1);
}

__device__ __forceinline__ void cg_solve(const float (&Rreg)[81],
                                         float rhs0, float rhs1,
                                         int iters, float a, int t, bool has1,
                                         float* pv, float* ap, float* red,
                                         float& z0o, float& z1o)
{
    const int jj = t & 15;
    const int e1 = t + 256;
    float z0 = 0.f, z1 = 0.f;
    float r0 = rhs0, r1 = has1 ? rhs1 : 0.f;
    float p0 = r0, p1 = r1;
    pv[(t / 25) * PVP + (t % 25)] = p0;
    if (has1) pv[(e1 / 25) * PVP + (e1 % 25)] = p1;
    float rr = block_sum256(r0 * r0 + r1 * r1, red, t);   // syncs cover pv writes

    for (int it = 0; it < iters; ++it) {
        float pld[25], acc[25];
        const float* pj = &pv[jj * PVP];
#pragma unroll
        for (int k = 0; k < 25; ++k) pld[k] = pj[k];
#pragma unroll
        for (int k = 0; k < 25; ++k) acc[k] = 0.f;
#pragma unroll
        for (int u = 0; u < 9; ++u) {
#pragma unroll
            for (int v = 0; v < 9; ++v) {
                const float Rv = Rreg[u * 9 + v];          // register (static idx)
#pragma unroll
                for (int c = 0; c < 5; ++c) {
                    if (c < u - 4 || c > u) continue;
                    const int aa = 4 + c - u;
#pragma unroll
                    for (int dd = 0; dd < 5; ++dd) {
                        if (dd < v - 4 || dd > v) continue;
                        const int bb = 4 + dd - v;
                        acc[aa * 5 + bb] += Rv * pld[c * 5 + dd];
                    }
                }
            }
        }
#pragma unroll
        for (int k = 0; k < 25; ++k) {
            float s2 = acc[k];
            s2 += __shfl_down(s2, 8, 16);
            s2 += __shfl_down(s2, 4, 16);
            s2 += __shfl_down(s2, 2, 16);
            s2 += __shfl_down(s2, 1, 16);
            acc[k] = s2;
        }
        if (jj == 0) {
#pragma unroll
            for (int k = 0; k < 25; ++k) ap[(t >> 4) * 25 + k] = acc[k];
        }
        __syncthreads();
        const float w0 = ap[t] + a * p0;
        const float w1 = has1 ? (ap[e1] + a * p1) : 0.f;
        const float2 dots = block_sum256_f2(p0 * w0 + p1 * w1,
                                            w0 * w0 + w1 * w1, red, t);
        const float pAp = dots.x, ww = dots.y;
        const bool ok = (pAp > 1e-30f);
        const float al  = ok ? rr / pAp : 0.f;
        z0 += al * p0; z1 += al * p1;
        if (it + 1 < iters) {
            const float rrn = ok ? fmaxf(al * al * ww - rr, 0.f) : rr;  // (r,w)=pAp
            const float be  = (rr > 1e-30f) ? rrn / rr : 0.f;
            rr = rrn;
            r0 -= al * w0; r1 -= al * w1;
            p0 = r0 + be * p0; p1 = r1 + be * p1;
            pv[(t / 25) * PVP + (t % 25)] = p0;
            if (has1) pv[(e1 / 25) * PVP + (e1 % 25)] = p1;
            __syncthreads();
        }
    }
    z0o = z0; z1o = z1;
}

__device__ __forceinline__ float conv_one(const float* __restrict__ act,
                                          const float* __restrict__ wall,
                                          int l, int idx)
{
    const int o = idx / 25, pix = idx % 25, yy = pix / 5, xx = pix % 5;
    float s = wall[17280 + l * 16 + o];
#pragma unroll
    for (int ky = 0; ky < 3; ++ky) {
        const int iy = yy + ky - 1;
        if ((unsigned)iy >= 5u) continue;
#pragma unroll
        for (int kx = 0; kx < 3; ++kx) {
            const int ix = xx + kx - 1;
            if ((unsigned)ix >= 5u) continue;
            const float* ip = act + (iy * 5 + ix) * 20;
            const float* wp = wall + l * 2880 + (o * 9 + ky * 3 + kx) * 20;
            const float4 a0 = *(const float4*)(ip);
            const float4 a1 = *(const float4*)(ip + 4);
            const float4 a2 = *(const float4*)(ip + 8);
            const float4 a3 = *(const float4*)(ip + 12);
            const float4 q0 = *(const float4*)(wp);
            const float4 q1 = *(const float4*)(wp + 4);
            const float4 q2 = *(const float4*)(wp + 8);
            const float4 q3 = *(const float4*)(wp + 12);
            s += a0.x * q0.x + a0.y * q0.y + a0.z * q0.z + a0.w * q0.w
               + a1.x * q1.x + a1.y * q1.y + a1.z * q1.z + a1.w * q1.w
               + a2.x * q2.x + a2.y * q2.y + a2.z * q2.z + a2.w * q2.w
               + a3.x * q3.x + a3.y * q3.y + a3.z * q3.z + a3.w * q3.w;
            if (l == 0) s += ip[16] * wp[16];
        }
    }
    return s;
}

__global__ __launch_bounds__(256, 1)
void solve_kernel(const float* __restrict__ R1, const float* __restrict__ R2,
                  const float* __restrict__ P1, const float* __restrict__ P2,
                  const float* __restrict__ d0, const float* __restrict__ alpha,
                  const float* __restrict__ beta, const float* __restrict__ reg,
                  const float* __restrict__ wrep,
                  float* __restrict__ out)
{
    __shared__ __align__(16) float Rl[256 * NLAG];   // 82944 B; weight overlay later
    __shared__ float pv[16 * PVP];
    __shared__ float ap[M];
    __shared__ float red[8];
    __shared__ float h0p[25 * 20];
    __shared__ float bufA[25 * 20], bufB[25 * 20];

    const int n = blockIdx.x, t = threadIdx.x;
    const bool has1 = (t < M - 256);   // t < 144
    const int e1 = t + 256;
    const float a = alpha[n] * (float)(H * W) * reg[0] / (float)(DS * DS * C);

    // stage R1 -> LDS (flat linear, async dma)
    {
        const char* g = (const char*)(R1 + (size_t)n * 256 * NLAG);
        char* l = (char*)Rl;
        for (int f = t; f < 5184; f += 256)
            gl_lds16(g + (size_t)f * 16, l + (size_t)f * 16);
    }
    const float rhs10 = P1[(size_t)n * M + t] + a * d0[(size_t)n * M + t];
    const float rhs11 = has1 ? (P1[(size_t)n * M + e1] + a * d0[(size_t)n * M + e1]) : 0.f;
    __syncthreads();   // drains the DMA

    float Rreg[81];
    {
        const float* Rrow = &Rl[t * NLAG];
#pragma unroll
        for (int i = 0; i < 81; ++i) Rreg[i] = Rrow[i];
    }
    __syncthreads();   // all Rl reads done before overwrite

    // issue R2 -> Rl DMA; completes under CG1 (drained at its first barrier)
    {
        const char* g = (const char*)(R2 + (size_t)n * 256 * NLAG);
        char* l = (char*)Rl;
        for (int f = t; f < 5184; f += 256)
            gl_lds16(g + (size_t)f * 16, l + (size_t)f * 16);
    }
    float z1a, z1b;
    cg_solve(Rreg, rhs10, rhs11, 3, a, t, has1, pv, ap, red, z1a, z1b);
    // CG1 passed many barriers -> Rl holds R2 now
    __syncthreads();   // ensure all waves past CG1 tail before Rreg reload
    {
        const float* Rrow = &Rl[t * NLAG];
#pragma unroll
        for (int i = 0; i < 81; ++i) Rreg[i] = Rrow[i];
    }
    __syncthreads();   // Rl reads done

    // issue weight-blob DMA into Rl overlay; completes under CG2
    {
        const char* g = (const char*)wrep;
        char* l = (char*)Rl;
        for (int f = t; f < WREP_CH; f += 256)
            gl_lds16(g + (size_t)f * 16, l + (size_t)f * 16);
    }
    const float rhs20 = P2[(size_t)n * M + t] + a * z1a;
    const float rhs21 = has1 ? (P2[(size_t)n * M + e1] + a * z1b) : 0.f;
    float z20, z21;
    cg_solve(Rreg, rhs20, rhs21, 7, a, t, has1, pv, ap, red, z20, z21);

    // ---- CNN. Activations [pix][ch] pitch 20; weights pre-repacked in Rl.
    const float* wall = (const float*)Rl;
    h0p[(t % 25) * 20 + t / 25] = z20;
    if (has1) h0p[(e1 % 25) * 20 + e1 / 25] = z21;
    if (t < 25) h0p[t * 20 + 16] = rsqrtf(beta[n]);
    __syncthreads();

#pragma unroll
    for (int l = 0; l < 6; ++l) {
        const float* act = (l == 0) ? h0p : ((l & 1) ? bufA : bufB);
        float s0 = conv_one(act, wall, l, t);
        float s1 = has1 ? conv_one(act, wall, l, e1) : 0.f;
        if (l < 5) { s0 = fmaxf(s0, 0.f); s1 = fmaxf(s1, 0.f); }
        else {
            s0 += h0p[(t % 25) * 20 + t / 25];
            if (has1) s1 += h0p[(e1 % 25) * 20 + e1 / 25];
        }
        if (l == 5) {
            out[(size_t)n * M + t] = s0;
            if (has1) out[(size_t)n * M + e1] = s1;
        } else {
            float* dstb = (l & 1) ? bufB : bufA;   // never aliases act
            dstb[(t % 25) * 20 + t / 25] = s0;
            if (has1) dstb[(e1 % 25) * 20 + e1 / 25] = s1;
        }
        __syncthreads();
    }
}

// ---------------------------------------------------------------------------
extern "C" void kernel_launch(void* const* d_in, const int* in_sizes, int n_in,
                              void* d_out, int out_size, void* d_ws, size_t ws_size,
                              hipStream_t stream)
{
    (void)in_sizes; (void)n_in; (void)out_size; (void)ws_size;
    const float* x1    = (const float*)d_in[0];
    const float* x2    = (const float*)d_in[1];
    const float* d0    = (const float*)d_in[2];
    const float* y1    = (const float*)d_in[3];
    const float* y2    = (const float*)d_in[4];
    const float* alpha = (const float*)d_in[5];
    const float* beta  = (const float*)d_in[6];
    const float* reg   = (const float*)d_in[7];
    const float* w1 = (const float*)d_in[8];  const float* b1 = (const float*)d_in[9];
    const float* w2 = (const float*)d_in[10]; const float* b2 = (const float*)d_in[11];
    const float* w3 = (const float*)d_in[12]; const float* b3 = (const float*)d_in[13];
    const float* w4 = (const float*)d_in[14]; const float* b4 = (const float*)d_in[15];
    const float* w5 = (const float*)d_in[16]; const float* b5 = (const float*)d_in[17];
    const float* w6 = (const float*)d_in[18]; const float* b6 = (const float*)d_in[19];
    float* out = (float*)d_out;

    char* wsb = (char*)d_ws;
    float* R1a = (float*)wsb;
    float* R1b = R1a + RSZ;
    float* R2a = R1b + RSZ;
    float* R2b = R2a + RSZ;
    float* P1  = R2b + RSZ;
    float* P2  = P1 + (size_t)NS * M;
    float* wrep = P2 + (size_t)NS * M;                         // 17376 floats

    autocorr_mfma<<<256, 512, 0, stream>>>(x1, x2, R1a, R1b, R2a, R2b);
    mid_kernel<<<1025 + CMB_BLOCKS, 256, 0, stream>>>(x1, x2, y1, y2, P1, P2,
                                                      w1, b1, w2, b2, w3, b3,
                                                      w4, b4, w5, b5, w6, b6,
                                                      wrep, R1a, R1b, R2a, R2b);
    solve_kernel<<<NS, 256, 0, stream>>>(R1a, R2a, P1, P2, d0, alpha, beta, reg,
                                         wrep, out);
}